// Round 2
// baseline (523.453 us; speedup 1.0000x reference)
//
#include <hip/hip_runtime.h>

// SMFNet: V0[i] = relu(X[i]·theta[i]+fb[i]) * V[i] + relu(X[i]·theta[i+1]+fb[i+1]) * V[i+1]
// where V[i] = relu(X[i]·xi^T + g_bias), indices mod N. Output [N,2] f32.

constexpr int NROWS = 524288;
constexpr int D     = 128;

__device__ __forceinline__ float dot8(const float4& a, const float4& b,
                                      const float4& c, const float4& d) {
    return a.x*c.x + a.y*c.y + a.z*c.z + a.w*c.w
         + b.x*d.x + b.y*d.y + b.z*d.z + b.w*d.w;
}

__global__ __launch_bounds__(256) void smf_kernel(
    const float* __restrict__ X,
    const float* __restrict__ theta,
    const float* __restrict__ f_bias,
    const float* __restrict__ xi,
    const float* __restrict__ g_bias,
    float* __restrict__ out)
{
    const int tid  = blockIdx.x * blockDim.x + threadIdx.x;
    const int wid  = tid >> 6;            // global wave id
    const int lane = threadIdx.x & 63;
    const int grp  = lane >> 4;           // 0..3: which of the wave's 4 rows
    const int q    = lane & 15;           // 0..15 within the row's 16-lane group
    const int col  = q * 8;               // this lane's 8-float column slice

    const int nwaves = (gridDim.x * blockDim.x) >> 6;

    // xi is [2][128]; per-lane slices, loaded once
    const float4 xi0a = *reinterpret_cast<const float4*>(xi + col);
    const float4 xi0b = *reinterpret_cast<const float4*>(xi + col + 4);
    const float4 xi1a = *reinterpret_cast<const float4*>(xi + D + col);
    const float4 xi1b = *reinterpret_cast<const float4*>(xi + D + col + 4);
    const float gb0 = g_bias[0];
    const float gb1 = g_bias[1];

    for (int base = wid * 4; base < NROWS; base += nwaves * 4) {
        const int i   = base + grp;                    // NROWS % 4 == 0 -> i < NROWS
        const int ip1 = (i + 1 == NROWS) ? 0 : i + 1;

        const float* xrow  = X     + (size_t)i   * D + col;
        const float* xnrow = X     + (size_t)ip1 * D + col;
        const float* trow  = theta + (size_t)i   * D + col;
        const float* tnrow = theta + (size_t)ip1 * D + col;

        const float4 xa  = *reinterpret_cast<const float4*>(xrow);
        const float4 xb  = *reinterpret_cast<const float4*>(xrow + 4);
        const float4 xna = *reinterpret_cast<const float4*>(xnrow);
        const float4 xnb = *reinterpret_cast<const float4*>(xnrow + 4);
        const float4 ta  = *reinterpret_cast<const float4*>(trow);
        const float4 tb  = *reinterpret_cast<const float4*>(trow + 4);
        const float4 tna = *reinterpret_cast<const float4*>(tnrow);
        const float4 tnb = *reinterpret_cast<const float4*>(tnrow + 4);

        const float fb  = f_bias[i];
        const float fbn = f_bias[ip1];

        float d_diag = dot8(xa, xb, ta, tb);       // X[i]·theta[i]
        float d_sup  = dot8(xa, xb, tna, tnb);     // X[i]·theta[i+1]
        float vi0    = dot8(xa, xb, xi0a, xi0b);   // X[i]·xi[0]
        float vi1    = dot8(xa, xb, xi1a, xi1b);   // X[i]·xi[1]
        float vn0    = dot8(xna, xnb, xi0a, xi0b); // X[i+1]·xi[0]
        float vn1    = dot8(xna, xnb, xi1a, xi1b); // X[i+1]·xi[1]

        // butterfly reduce across the 16-lane group (masks 8,4,2,1 stay in-group)
        #pragma unroll
        for (int m = 8; m >= 1; m >>= 1) {
            d_diag += __shfl_xor(d_diag, m, 64);
            d_sup  += __shfl_xor(d_sup,  m, 64);
            vi0    += __shfl_xor(vi0,    m, 64);
            vi1    += __shfl_xor(vi1,    m, 64);
            vn0    += __shfl_xor(vn0,    m, 64);
            vn1    += __shfl_xor(vn1,    m, 64);
        }

        if (q == 0) {
            const float w_diag = fmaxf(d_diag + fb,  0.f);
            const float w_sup  = fmaxf(d_sup  + fbn, 0.f);
            const float v0 = fmaxf(vi0 + gb0, 0.f);
            const float v1 = fmaxf(vi1 + gb1, 0.f);
            const float u0 = fmaxf(vn0 + gb0, 0.f);
            const float u1 = fmaxf(vn1 + gb1, 0.f);
            float2 o;
            o.x = w_diag * v0 + w_sup * u0;
            o.y = w_diag * v1 + w_sup * u1;
            *reinterpret_cast<float2*>(out + (size_t)i * 2) = o;
        }
    }
}

extern "C" void kernel_launch(void* const* d_in, const int* in_sizes, int n_in,
                              void* d_out, int out_size, void* d_ws, size_t ws_size,
                              hipStream_t stream) {
    const float* X      = (const float*)d_in[0];
    const float* theta  = (const float*)d_in[1];
    const float* f_bias = (const float*)d_in[2];
    const float* xi     = (const float*)d_in[3];
    const float* g_bias = (const float*)d_in[4];
    float* out = (float*)d_out;

    const int threads = 256;
    const int blocks  = 4096;   // 16384 waves -> 65536 rows/sweep -> 8 sweeps
    smf_kernel<<<blocks, threads, 0, stream>>>(X, theta, f_bias, xi, g_bias, out);
}

// Round 3
// 508.832 us; speedup vs baseline: 1.0287x; 1.0287x over previous
//
#include <hip/hip_runtime.h>

// SMFNet: V0[i] = relu(X[i]·theta[i]+fb[i]) * V[i] + relu(X[i]·theta[i+1]+fb[i+1]) * V[i+1]
// where V[i] = relu(X[i]·xi^T + g_bias), indices mod N. Output [N,2] f32.
//
// One 4-row tile per wave, no loop: all loads independent, issued before use.
// __launch_bounds__(256,4): 4 waves/EU min -> 128-VGPR cap, enough for the
// ~70-reg live set (prev round's (256) default pinned VGPRs at 32 and the
// compiler serialized the loads -> 171us latency-bound).

constexpr int NROWS = 524288;
constexpr int D     = 128;

__device__ __forceinline__ float dot8(const float4& a, const float4& b,
                                      const float4& c, const float4& d) {
    return a.x*c.x + a.y*c.y + a.z*c.z + a.w*c.w
         + b.x*d.x + b.y*d.y + b.z*d.z + b.w*d.w;
}

__global__ __launch_bounds__(256, 4) void smf_kernel(
    const float* __restrict__ X,
    const float* __restrict__ theta,
    const float* __restrict__ f_bias,
    const float* __restrict__ xi,
    const float* __restrict__ g_bias,
    float* __restrict__ out)
{
    const int tid  = blockIdx.x * blockDim.x + threadIdx.x;
    const int wid  = tid >> 6;            // global wave id, one tile each
    const int lane = threadIdx.x & 63;
    const int grp  = lane >> 4;           // 0..3: which of the wave's 4 rows
    const int q    = lane & 15;           // 0..15 within the row's 16-lane group
    const int col  = q * 8;               // this lane's 8-float column slice

    const int i   = wid * 4 + grp;                 // < NROWS by grid construction
    const int ip1 = (i + 1 == NROWS) ? 0 : i + 1;

    const float* xrow  = X     + (size_t)i   * D + col;
    const float* xnrow = X     + (size_t)ip1 * D + col;
    const float* trow  = theta + (size_t)i   * D + col;
    const float* tnrow = theta + (size_t)ip1 * D + col;

    // 12 independent dwordx4 loads — let them all fly before any use.
    const float4 xa   = *reinterpret_cast<const float4*>(xrow);
    const float4 xb   = *reinterpret_cast<const float4*>(xrow + 4);
    const float4 xna  = *reinterpret_cast<const float4*>(xnrow);
    const float4 xnb  = *reinterpret_cast<const float4*>(xnrow + 4);
    const float4 ta   = *reinterpret_cast<const float4*>(trow);
    const float4 tb   = *reinterpret_cast<const float4*>(trow + 4);
    const float4 tna  = *reinterpret_cast<const float4*>(tnrow);
    const float4 tnb  = *reinterpret_cast<const float4*>(tnrow + 4);
    const float4 xi0a = *reinterpret_cast<const float4*>(xi + col);
    const float4 xi0b = *reinterpret_cast<const float4*>(xi + col + 4);
    const float4 xi1a = *reinterpret_cast<const float4*>(xi + D + col);
    const float4 xi1b = *reinterpret_cast<const float4*>(xi + D + col + 4);

    const float fb  = f_bias[i];
    const float fbn = f_bias[ip1];
    const float gb0 = g_bias[0];
    const float gb1 = g_bias[1];

    float d_diag = dot8(xa, xb, ta, tb);       // X[i]·theta[i]
    float d_sup  = dot8(xa, xb, tna, tnb);     // X[i]·theta[i+1]
    float vi0    = dot8(xa, xb, xi0a, xi0b);   // X[i]·xi[0]
    float vi1    = dot8(xa, xb, xi1a, xi1b);   // X[i]·xi[1]
    float vn0    = dot8(xna, xnb, xi0a, xi0b); // X[i+1]·xi[0]
    float vn1    = dot8(xna, xnb, xi1a, xi1b); // X[i+1]·xi[1]

    // butterfly reduce across the 16-lane group (masks 8,4,2,1 stay in-group)
    #pragma unroll
    for (int m = 8; m >= 1; m >>= 1) {
        d_diag += __shfl_xor(d_diag, m, 64);
        d_sup  += __shfl_xor(d_sup,  m, 64);
        vi0    += __shfl_xor(vi0,    m, 64);
        vi1    += __shfl_xor(vi1,    m, 64);
        vn0    += __shfl_xor(vn0,    m, 64);
        vn1    += __shfl_xor(vn1,    m, 64);
    }

    if (q == 0) {
        const float w_diag = fmaxf(d_diag + fb,  0.f);
        const float w_sup  = fmaxf(d_sup  + fbn, 0.f);
        const float v0 = fmaxf(vi0 + gb0, 0.f);
        const float v1 = fmaxf(vi1 + gb1, 0.f);
        const float u0 = fmaxf(vn0 + gb0, 0.f);
        const float u1 = fmaxf(vn1 + gb1, 0.f);
        float2 o;
        o.x = w_diag * v0 + w_sup * u0;
        o.y = w_diag * v1 + w_sup * u1;
        *reinterpret_cast<float2*>(out + (size_t)i * 2) = o;
    }
}

extern "C" void kernel_launch(void* const* d_in, const int* in_sizes, int n_in,
                              void* d_out, int out_size, void* d_ws, size_t ws_size,
                              hipStream_t stream) {
    const float* X      = (const float*)d_in[0];
    const float* theta  = (const float*)d_in[1];
    const float* f_bias = (const float*)d_in[2];
    const float* xi     = (const float*)d_in[3];
    const float* g_bias = (const float*)d_in[4];
    float* out = (float*)d_out;

    const int threads = 256;                       // 4 waves/block, 4 rows/wave
    const int blocks  = NROWS / 16;                // 32768: one-shot, no loop
    smf_kernel<<<blocks, threads, 0, stream>>>(X, theta, f_bias, xi, g_bias, out);
}

// Round 4
// 507.458 us; speedup vs baseline: 1.0315x; 1.0027x over previous
//
#include <hip/hip_runtime.h>

// SMFNet: V0[i] = relu(X[i].theta[i]+fb[i]) * V[i] + relu(X[i].theta[i+1]+fb[i+1]) * V[i+1]
// where V[i] = relu(X[i].xi^T + g_bias), indices mod N. Output [N,2] f32.
//
// Structure: 16 lanes per row (8 floats/lane, 32B contiguous), 4 rows per wave,
// 8 tiles per wave with a 2-deep software pipeline: tile t+1's 12 independent
// dwordx4 loads are issued before tile t's compute, so the HBM round-trip of
// the next tile hides under the current tile's dots + shuffle reduction.
// Round-3 post-mortem: one-shot waves (1 tile/wave) left one un-overlappable
// latency bubble per wave -> 156us with every pipe <25% busy.

constexpr int NROWS = 524288;
constexpr int D     = 128;
constexpr int TPW   = 8;   // tiles per wave (4 rows each) -> 32 rows/wave

struct Tile {
    float4 xa, xb, xna, xnb, ta, tb, tna, tnb;
    float fb, fbn;
};

__device__ __forceinline__ float dot8(const float4& a, const float4& b,
                                      const float4& c, const float4& d) {
    return a.x*c.x + a.y*c.y + a.z*c.z + a.w*c.w
         + b.x*d.x + b.y*d.y + b.z*d.z + b.w*d.w;
}

__device__ __forceinline__ void load_tile(int i, int col,
    const float* __restrict__ X, const float* __restrict__ theta,
    const float* __restrict__ f_bias, Tile& t)
{
    const int ip1 = (i + 1 == NROWS) ? 0 : i + 1;
    const float* xrow  = X     + (size_t)i   * D + col;
    const float* xnrow = X     + (size_t)ip1 * D + col;
    const float* trow  = theta + (size_t)i   * D + col;
    const float* tnrow = theta + (size_t)ip1 * D + col;
    t.xa  = *reinterpret_cast<const float4*>(xrow);
    t.xb  = *reinterpret_cast<const float4*>(xrow + 4);
    t.xna = *reinterpret_cast<const float4*>(xnrow);
    t.xnb = *reinterpret_cast<const float4*>(xnrow + 4);
    t.ta  = *reinterpret_cast<const float4*>(trow);
    t.tb  = *reinterpret_cast<const float4*>(trow + 4);
    t.tna = *reinterpret_cast<const float4*>(tnrow);
    t.tnb = *reinterpret_cast<const float4*>(tnrow + 4);
    t.fb  = f_bias[i];
    t.fbn = f_bias[ip1];
}

__device__ __forceinline__ void compute_store(const Tile& t, int i, int q,
    const float4& xi0a, const float4& xi0b, const float4& xi1a, const float4& xi1b,
    float gb0, float gb1, float* __restrict__ out)
{
    float d_diag = dot8(t.xa,  t.xb,  t.ta,  t.tb);   // X[i].theta[i]
    float d_sup  = dot8(t.xa,  t.xb,  t.tna, t.tnb);  // X[i].theta[i+1]
    float vi0    = dot8(t.xa,  t.xb,  xi0a,  xi0b);   // X[i].xi[0]
    float vi1    = dot8(t.xa,  t.xb,  xi1a,  xi1b);   // X[i].xi[1]
    float vn0    = dot8(t.xna, t.xnb, xi0a,  xi0b);   // X[i+1].xi[0]
    float vn1    = dot8(t.xna, t.xnb, xi1a,  xi1b);   // X[i+1].xi[1]

    #pragma unroll
    for (int m = 8; m >= 1; m >>= 1) {
        d_diag += __shfl_xor(d_diag, m, 64);
        d_sup  += __shfl_xor(d_sup,  m, 64);
        vi0    += __shfl_xor(vi0,    m, 64);
        vi1    += __shfl_xor(vi1,    m, 64);
        vn0    += __shfl_xor(vn0,    m, 64);
        vn1    += __shfl_xor(vn1,    m, 64);
    }

    if (q == 0) {
        const float w_diag = fmaxf(d_diag + t.fb,  0.f);
        const float w_sup  = fmaxf(d_sup  + t.fbn, 0.f);
        const float v0 = fmaxf(vi0 + gb0, 0.f);
        const float v1 = fmaxf(vi1 + gb1, 0.f);
        const float u0 = fmaxf(vn0 + gb0, 0.f);
        const float u1 = fmaxf(vn1 + gb1, 0.f);
        float2 o;
        o.x = w_diag * v0 + w_sup * u0;
        o.y = w_diag * v1 + w_sup * u1;
        *reinterpret_cast<float2*>(out + (size_t)i * 2) = o;
    }
}

__global__ __launch_bounds__(256, 3) void smf_kernel(
    const float* __restrict__ X,
    const float* __restrict__ theta,
    const float* __restrict__ f_bias,
    const float* __restrict__ xi,
    const float* __restrict__ g_bias,
    float* __restrict__ out)
{
    const int tid  = blockIdx.x * blockDim.x + threadIdx.x;
    const int wid  = tid >> 6;
    const int lane = threadIdx.x & 63;
    const int grp  = lane >> 4;          // 0..3: row within tile
    const int q    = lane & 15;          // position within 16-lane row group
    const int col  = q * 8;              // 8-float (32B) contiguous slice

    const int row0 = wid * (4 * TPW) + grp;   // this group's row in tile 0

    // xi [2][128] + g_bias: tiny, L1-resident
    const float4 xi0a = *reinterpret_cast<const float4*>(xi + col);
    const float4 xi0b = *reinterpret_cast<const float4*>(xi + col + 4);
    const float4 xi1a = *reinterpret_cast<const float4*>(xi + D + col);
    const float4 xi1b = *reinterpret_cast<const float4*>(xi + D + col + 4);
    const float gb0 = g_bias[0];
    const float gb1 = g_bias[1];

    Tile t0, t1;
    load_tile(row0, col, X, theta, f_bias, t0);

    #pragma unroll
    for (int t = 0; t < TPW; ++t) {
        Tile& cur = (t & 1) ? t1 : t0;   // full unroll -> static indexing
        Tile& nxt = (t & 1) ? t0 : t1;
        if (t + 1 < TPW)
            load_tile(row0 + (t + 1) * 4, col, X, theta, f_bias, nxt);
        compute_store(cur, row0 + t * 4, q, xi0a, xi0b, xi1a, xi1b, gb0, gb1, out);
    }
}

extern "C" void kernel_launch(void* const* d_in, const int* in_sizes, int n_in,
                              void* d_out, int out_size, void* d_ws, size_t ws_size,
                              hipStream_t stream) {
    const float* X      = (const float*)d_in[0];
    const float* theta  = (const float*)d_in[1];
    const float* f_bias = (const float*)d_in[2];
    const float* xi     = (const float*)d_in[3];
    const float* g_bias = (const float*)d_in[4];
    float* out = (float*)d_out;

    const int threads = 256;                            // 4 waves/block
    const int blocks  = NROWS / (4 * TPW * 4);          // 4096 blocks, 16384 waves
    smf_kernel<<<blocks, threads, 0, stream>>>(X, theta, f_bias, xi, g_bias, out);
}